// Round 8
// baseline (1149.543 us; speedup 1.0000x reference)
//
#include <hip/hip_runtime.h>
#include <math.h>

#define NN 100000
#define NE 1600000
#define DD 64
#define NBUK 782          // ceil(NN/128), bucket = dst>>7

typedef __attribute__((ext_vector_type(8))) short short8;
typedef __attribute__((ext_vector_type(4))) float f32x4;

__device__ __forceinline__ float gelu_exact(float v) {
    return 0.5f * v * (1.0f + erff(v * 0.7071067811865475f));
}

__device__ __forceinline__ unsigned short f2bf(float f) {   // RNE
    unsigned u = __float_as_uint(f);
    return (unsigned short)((u + 0x7FFFu + ((u >> 16) & 1u)) >> 16);
}
__device__ __forceinline__ float bf2f(unsigned short h) {
    return __uint_as_float((unsigned)h << 16);
}
__device__ __forceinline__ void split8(const float* a, short8& hi, short8& lo) {
    float4 x0 = *(const float4*)a;
    float4 x1 = *(const float4*)(a + 4);
    float v[8] = {x0.x, x0.y, x0.z, x0.w, x1.x, x1.y, x1.z, x1.w};
    #pragma unroll
    for (int i = 0; i < 8; ++i) {
        unsigned short h = f2bf(v[i]);
        hi[i] = (short)h;
        lo[i] = (short)f2bf(v[i] - bf2f(h));
    }
}

__device__ __forceinline__ float wave_max64(float v) {
    #pragma unroll
    for (int o = 32; o > 0; o >>= 1) v = fmaxf(v, __shfl_xor(v, o));
    return v;
}
__device__ __forceinline__ float wave_sum64(float v) {
    #pragma unroll
    for (int o = 32; o > 0; o >>= 1) v += __shfl_xor(v, o);
    return v;
}

// K0P: build bf16 hi/lo split weight buffers:
//   [0,8192)      Bmix[d][kk]: kk<64 -> alpha*Wp[d][kk], else beta*Wn[d][kk-64]
//   [8192,16384)  w1 linear   [j][k]
//   [16384,24576) w2 linear   [d][j]
__global__ __launch_bounds__(256) void k0prep(
    const float* __restrict__ Wp, const float* __restrict__ Wn,
    const float* __restrict__ w1, const float* __restrict__ w2,
    const float* __restrict__ cf,
    unsigned short* __restrict__ wh, unsigned short* __restrict__ wl)
{
    int t = blockIdx.x * 256 + threadIdx.x;   // 24576 total
    float alpha = 1.0f / (1.0f + __expf(-cf[0]));
    float beta  = 1.0f - alpha;
    float v;
    if (t < 8192) {
        int d = t >> 7, k = t & 127;
        v = (k < 64) ? alpha * Wp[d * 64 + k] : beta * Wn[d * 64 + (k - 64)];
    } else if (t < 16384) {
        v = w1[t - 8192];
    } else {
        v = w2[t - 16384];
    }
    unsigned short h = f2bf(v);
    wh[t] = h;
    wl[t] = f2bf(v - bf2f(h));
}

// K1: per-node attention projections
__global__ __launch_bounds__(256) void k1_scores(
    const float* __restrict__ x, const float* __restrict__ attw,
    float* __restrict__ s1, float* __restrict__ s2)
{
    int n = blockIdx.x * 256 + threadIdx.x;
    if (n >= NN) return;
    const float4* x4 = (const float4*)(x + (size_t)n * DD);
    float a = 0.f, b = 0.f;
    #pragma unroll
    for (int i = 0; i < DD/4; ++i) {
        float4 v = x4[i];
        a += v.x*attw[4*i+0] + v.y*attw[4*i+1] + v.z*attw[4*i+2] + v.w*attw[4*i+3];
        b += v.x*attw[DD+4*i+0] + v.y*attw[DD+4*i+1] + v.z*attw[DD+4*i+2] + v.w*attw[DD+4*i+3];
    }
    s1[n] = a;
    s2[n] = b;
}

// KHC: coarse histogram over 782 buckets
__global__ __launch_bounds__(256) void kh_coarse(
    const int* __restrict__ ei, int* __restrict__ bcount)
{
    int e = blockIdx.x * 256 + threadIdx.x;
    if (e >= NE) return;
    atomicAdd(bcount + (ei[NE + e] >> 7), 1);
}

// KBS: single-block exclusive scan of 782 bucket counts -> bbase, bpos
__global__ __launch_bounds__(1024) void ks_bscan(
    const int* __restrict__ bcount, int* __restrict__ bbase, int* __restrict__ bpos)
{
    __shared__ int sa[1024], sb[1024];
    int t = threadIdx.x;
    int v = (t < NBUK) ? bcount[t] : 0;
    sa[t] = v;
    __syncthreads();
    int* s = sa; int* d = sb;
    #pragma unroll
    for (int o = 1; o < 1024; o <<= 1) {
        d[t] = s[t] + ((t >= o) ? s[t - o] : 0);
        __syncthreads();
        int* tmp = s; s = d; d = tmp;
    }
    if (t < NBUK) {
        int excl = s[t] - v;
        bbase[t] = excl;
        bpos[t]  = excl;
    }
    if (t == 0) bbase[NBUK] = NE;
}

// KSCAT1: coarse scatter into bucket regions: {src | local<<17, rf}
__global__ __launch_bounds__(256) void kscat1(
    const int* __restrict__ ei, const float* __restrict__ rf,
    int* __restrict__ bpos, uint2* __restrict__ tmp)
{
    int e = blockIdx.x * 256 + threadIdx.x;
    if (e >= NE) return;
    int src = ei[e];
    int dst = ei[NE + e];
    int b = dst >> 7;
    unsigned packed = (unsigned)src | ((unsigned)(dst & 127) << 17);
    int p = atomicAdd(bpos + b, 1);
    tmp[p] = make_uint2(packed, __float_as_uint(rf[e]));
}

// KSCAT2: block-per-bucket fine sort: local histogram -> scan -> off[] + final scatter
__global__ __launch_bounds__(256) void kscat2(
    const uint2* __restrict__ tmp, const int* __restrict__ bbase,
    int* __restrict__ off, uint2* __restrict__ sorted)
{
    __shared__ int hist[128], scn[128], tick[128];
    int b   = blockIdx.x;
    int tid = threadIdx.x;
    int s = bbase[b], e = bbase[b + 1];

    if (tid < 128) { hist[tid] = 0; tick[tid] = 0; }
    __syncthreads();

    for (int i = s + tid; i < e; i += 256)
        atomicAdd(&hist[tmp[i].x >> 17], 1);
    __syncthreads();

    // inclusive Hillis-Steele scan of hist -> scn (128 entries)
    if (tid < 128) scn[tid] = hist[tid];
    __syncthreads();
    #pragma unroll
    for (int o = 1; o < 128; o <<= 1) {
        int v = (tid < 128 && tid >= o) ? scn[tid - o] : 0;
        __syncthreads();
        if (tid < 128) scn[tid] += v;
        __syncthreads();
    }

    int nb0 = b * 128;
    if (tid < 128 && nb0 + tid < NN) off[nb0 + tid] = s + scn[tid] - hist[tid];
    if (b == NBUK - 1 && tid == 0) off[NN] = NE;
    __syncthreads();

    for (int i = s + tid; i < e; i += 256) {
        uint2 pr = tmp[i];
        int l = pr.x >> 17;
        int t = atomicAdd(&tick[l], 1);
        int p = s + (scn[l] - hist[l]) + t;
        sorted[p] = make_uint2(pr.x & 0x1FFFFu, pr.y);
    }
}

// K4A: wave-per-node fused softmax + aggregation. uv[n] = {u, v}
__global__ __launch_bounds__(256) void k4a_agg(
    const float2* __restrict__ sorted, const int* __restrict__ off,
    const float* __restrict__ s1, const float* __restrict__ s2,
    const float* __restrict__ x, float* __restrict__ uv)
{
    int lane = threadIdx.x & 63;
    int n = blockIdx.x * 4 + (threadIdx.x >> 6);
    int r0 = off[n], r1 = off[n + 1];
    float s2n = s2[n];

    float m = -INFINITY, den = 0.f;
    for (int base = r0; base < r1; base += 64) {
        int idx = base + lane;
        float sc = -INFINITY;
        if (idx < r1) {
            float2 p = sorted[idx];
            sc = s1[__float_as_int(p.x)] + s2n;
        }
        float cm = wave_max64(sc);
        float nm = fmaxf(m, cm);
        float term = (idx < r1) ? __expf(sc - nm) : 0.f;
        den = den * __expf(m - nm) + wave_sum64(term);
        m = nm;
    }

    float u = 0.f, v = 0.f;
    for (int base = r0; base < r1; base += 64) {
        int idx = base + lane;
        int cnt = min(64, r1 - base);
        int srcl = 0; float rfl = 0.f, el = 0.f;
        if (idx < r1) {
            float2 p = sorted[idx];
            srcl = __float_as_int(p.x);
            rfl = p.y;
            el = __expf(s1[srcl] + s2n - m);
        }
        int j = 0;
        for (; j + 4 <= cnt; j += 4) {
            int   a0 = __shfl(srcl, j+0), a1 = __shfl(srcl, j+1);
            int   a2 = __shfl(srcl, j+2), a3 = __shfl(srcl, j+3);
            float e0 = __shfl(el, j+0), e1 = __shfl(el, j+1);
            float e2 = __shfl(el, j+2), e3 = __shfl(el, j+3);
            float f0 = __shfl(rfl, j+0), f1 = __shfl(rfl, j+1);
            float f2 = __shfl(rfl, j+2), f3 = __shfl(rfl, j+3);
            float x0 = x[(size_t)a0 * DD + lane];
            float x1 = x[(size_t)a1 * DD + lane];
            float x2 = x[(size_t)a2 * DD + lane];
            float x3 = x[(size_t)a3 * DD + lane];
            v += e0*x0 + e1*x1 + e2*x2 + e3*x3;
            u += e0*f0*x0 + e1*f1*x1 + e2*f2*x2 + e3*f3*x3;
        }
        for (; j < cnt; ++j) {
            int   sj = __shfl(srcl, j);
            float ej = __shfl(el,   j);
            float fj = __shfl(rfl,  j);
            float xv = x[(size_t)sj * DD + lane];
            v += ej * xv;
            u += ej * fj * xv;
        }
    }
    float inv = (r1 > r0) ? 1.f / den : 0.f;
    uv[(size_t)n * 2*DD + lane]      = u * inv;
    uv[(size_t)n * 2*DD + DD + lane] = v * inv;
}

// K4B: MFMA split-bf16 GEMM: agg[NN,64] = uv[NN,128] @ Bmix[128,64]
__global__ __launch_bounds__(256) void k4b_mfma(
    const float* __restrict__ uv, const unsigned short* __restrict__ wh,
    const unsigned short* __restrict__ wl, float* __restrict__ agg)
{
    int lane = threadIdx.x & 63;
    int wv   = threadIdx.x >> 6;
    int quad = lane >> 4, l16 = lane & 15;
    int nb = blockIdx.x * 64 + wv * 16;
    const float* arow = uv + (size_t)(nb + l16) * 128;

    f32x4 acc[4] = {};
    #pragma unroll
    for (int ks = 0; ks < 4; ++ks) {
        int k0 = ks * 32 + quad * 8;
        short8 ah, al;
        split8(arow + k0, ah, al);
        #pragma unroll
        for (int nt = 0; nt < 4; ++nt) {
            short8 bh = *(const short8*)(wh + (size_t)(nt*16 + l16)*128 + k0);
            short8 bl = *(const short8*)(wl + (size_t)(nt*16 + l16)*128 + k0);
            acc[nt] = __builtin_amdgcn_mfma_f32_16x16x32_bf16(ah, bh, acc[nt], 0, 0, 0);
            acc[nt] = __builtin_amdgcn_mfma_f32_16x16x32_bf16(al, bh, acc[nt], 0, 0, 0);
            acc[nt] = __builtin_amdgcn_mfma_f32_16x16x32_bf16(ah, bl, acc[nt], 0, 0, 0);
        }
    }
    #pragma unroll
    for (int r = 0; r < 4; ++r) {
        int n = nb + quad * 4 + r;
        if (n < NN) {
            #pragma unroll
            for (int nt = 0; nt < 4; ++nt)
                agg[(size_t)n * 64 + nt*16 + l16] = acc[nt][r];
        }
    }
}

// K5H: h = LN1(gelu(agg) + x) -> hbuf
__global__ __launch_bounds__(256) void k5h_ln1(
    const float* __restrict__ agg, const float* __restrict__ x,
    const float* __restrict__ g1, const float* __restrict__ be1,
    float* __restrict__ hbuf)
{
    int n = blockIdx.x * 256 + threadIdx.x;
    if (n >= NN) return;
    float h[DD];
    const float4* a4 = (const float4*)(agg + (size_t)n * DD);
    const float4* x4 = (const float4*)(x   + (size_t)n * DD);
    #pragma unroll
    for (int i = 0; i < DD/4; ++i) {
        float4 av = a4[i];
        float4 xv = x4[i];
        h[4*i+0] = gelu_exact(av.x) + xv.x;
        h[4*i+1] = gelu_exact(av.y) + xv.y;
        h[4*i+2] = gelu_exact(av.z) + xv.z;
        h[4*i+3] = gelu_exact(av.w) + xv.w;
    }
    float mu = 0.f;
    #pragma unroll
    for (int d = 0; d < DD; ++d) mu += h[d];
    mu *= (1.0f/DD);
    float var = 0.f;
    #pragma unroll
    for (int d = 0; d < DD; ++d) { float t = h[d]-mu; var += t*t; }
    var *= (1.0f/DD);
    float rs = rsqrtf(var + 1e-5f);
    float4* h4 = (float4*)(hbuf + (size_t)n * DD);
    #pragma unroll
    for (int i = 0; i < DD/4; ++i) {
        float4 o;
        o.x = (h[4*i+0]-mu)*rs*g1[4*i+0] + be1[4*i+0];
        o.y = (h[4*i+1]-mu)*rs*g1[4*i+1] + be1[4*i+1];
        o.z = (h[4*i+2]-mu)*rs*g1[4*i+2] + be1[4*i+2];
        o.w = (h[4*i+3]-mu)*rs*g1[4*i+3] + be1[4*i+3];
        h4[i] = o;
    }
}

// K5A: MFMA GEMM1 + gelu: G[NN,128] = gelu(h[NN,64] @ w1^T + b1)
__global__ __launch_bounds__(256) void k5a_mfma(
    const float* __restrict__ hbuf, const unsigned short* __restrict__ w1h,
    const unsigned short* __restrict__ w1l, const float* __restrict__ bb1,
    float* __restrict__ G)
{
    int lane = threadIdx.x & 63;
    int wv   = threadIdx.x >> 6;
    int quad = lane >> 4, l16 = lane & 15;
    int nb = blockIdx.x * 64 + wv * 16;
    const float* arow = hbuf + (size_t)(nb + l16) * 64;

    f32x4 acc[8] = {};
    #pragma unroll
    for (int ks = 0; ks < 2; ++ks) {
        int k0 = ks * 32 + quad * 8;
        short8 ah, al;
        split8(arow + k0, ah, al);
        #pragma unroll
        for (int nt = 0; nt < 8; ++nt) {
            short8 bh = *(const short8*)(w1h + (size_t)(nt*16 + l16)*64 + k0);
            short8 bl = *(const short8*)(w1l + (size_t)(nt*16 + l16)*64 + k0);
            acc[nt] = __builtin_amdgcn_mfma_f32_16x16x32_bf16(ah, bh, acc[nt], 0, 0, 0);
            acc[nt] = __builtin_amdgcn_mfma_f32_16x16x32_bf16(al, bh, acc[nt], 0, 0, 0);
            acc[nt] = __builtin_amdgcn_mfma_f32_16x16x32_bf16(ah, bl, acc[nt], 0, 0, 0);
        }
    }
    #pragma unroll
    for (int nt = 0; nt < 8; ++nt) {
        float b1v = bb1[nt*16 + l16];
        #pragma unroll
        for (int r = 0; r < 4; ++r) {
            int n = nb + quad * 4 + r;
            if (n < NN)
                G[(size_t)n * 128 + nt*16 + l16] = gelu_exact(acc[nt][r] + b1v);
        }
    }
}

// K5B: MFMA GEMM2: mbuf[NN,64] = G[NN,128] @ w2^T
__global__ __launch_bounds__(256) void k5b_mfma(
    const float* __restrict__ G, const unsigned short* __restrict__ w2h,
    const unsigned short* __restrict__ w2l, float* __restrict__ mbuf)
{
    int lane = threadIdx.x & 63;
    int wv   = threadIdx.x >> 6;
    int quad = lane >> 4, l16 = lane & 15;
    int nb = blockIdx.x * 64 + wv * 16;
    const float* arow = G + (size_t)(nb + l16) * 128;

    f32x4 acc[4] = {};
    #pragma unroll
    for (int ks = 0; ks < 4; ++ks) {
        int k0 = ks * 32 + quad * 8;
        short8 ah, al;
        split8(arow + k0, ah, al);
        #pragma unroll
        for (int nt = 0; nt < 4; ++nt) {
            short8 bh = *(const short8*)(w2h + (size_t)(nt*16 + l16)*128 + k0);
            short8 bl = *(const short8*)(w2l + (size_t)(nt*16 + l16)*128 + k0);
            acc[nt] = __builtin_amdgcn_mfma_f32_16x16x32_bf16(ah, bh, acc[nt], 0, 0, 0);
            acc[nt] = __builtin_amdgcn_mfma_f32_16x16x32_bf16(al, bh, acc[nt], 0, 0, 0);
            acc[nt] = __builtin_amdgcn_mfma_f32_16x16x32_bf16(ah, bl, acc[nt], 0, 0, 0);
        }
    }
    #pragma unroll
    for (int r = 0; r < 4; ++r) {
        int n = nb + quad * 4 + r;
        if (n < NN) {
            #pragma unroll
            for (int nt = 0; nt < 4; ++nt)
                mbuf[(size_t)n * 64 + nt*16 + l16] = acc[nt][r];
        }
    }
}

// K5C: out = LN2(mbuf + hbuf + b2)
__global__ __launch_bounds__(256) void k5c_ln2(
    const float* __restrict__ mbuf, const float* __restrict__ hbuf,
    const float* __restrict__ bb2,
    const float* __restrict__ g2, const float* __restrict__ be2,
    float* __restrict__ out)
{
    int n = blockIdx.x * 256 + threadIdx.x;
    if (n >= NN) return;
    float m[DD];
    const float4* m4 = (const float4*)(mbuf + (size_t)n * DD);
    const float4* h4 = (const float4*)(hbuf + (size_t)n * DD);
    #pragma unroll
    for (int i = 0; i < DD/4; ++i) {
        float4 mv = m4[i];
        float4 hv = h4[i];
        m[4*i+0] = mv.x + hv.x + bb2[4*i+0];
        m[4*i+1] = mv.y + hv.y + bb2[4*i+1];
        m[4*i+2] = mv.z + hv.z + bb2[4*i+2];
        m[4*i+3] = mv.w + hv.w + bb2[4*i+3];
    }
    float mu = 0.f;
    #pragma unroll
    for (int d = 0; d < DD; ++d) mu += m[d];
    mu *= (1.0f/DD);
    float var = 0.f;
    #pragma unroll
    for (int d = 0; d < DD; ++d) { float t = m[d]-mu; var += t*t; }
    var *= (1.0f/DD);
    float rs = rsqrtf(var + 1e-5f);
    float4* o4 = (float4*)(out + (size_t)n * DD);
    #pragma unroll
    for (int i = 0; i < DD/4; ++i) {
        float4 o;
        o.x = (m[4*i+0]-mu)*rs*g2[4*i+0] + be2[4*i+0];
        o.y = (m[4*i+1]-mu)*rs*g2[4*i+1] + be2[4*i+1];
        o.z = (m[4*i+2]-mu)*rs*g2[4*i+2] + be2[4*i+2];
        o.w = (m[4*i+3]-mu)*rs*g2[4*i+3] + be2[4*i+3];
        o4[i] = o;
    }
}

extern "C" void kernel_launch(void* const* d_in, const int* in_sizes, int n_in,
                              void* d_out, int out_size, void* d_ws, size_t ws_size,
                              hipStream_t stream) {
    const float* x    = (const float*)d_in[0];
    const int*   ei   = (const int*)d_in[1];
    const float* rf   = (const float*)d_in[2];
    const float* Wp   = (const float*)d_in[3];
    const float* Wn   = (const float*)d_in[4];
    const float* attw = (const float*)d_in[5];
    const float* cf   = (const float*)d_in[6];
    const float* w1   = (const float*)d_in[7];
    const float* b1   = (const float*)d_in[8];
    const float* w2   = (const float*)d_in[9];
    const float* b2   = (const float*)d_in[10];
    const float* g1   = (const float*)d_in[11];
    const float* be1  = (const float*)d_in[12];
    const float* g2   = (const float*)d_in[13];
    const float* be2  = (const float*)d_in[14];
    float* out = (float*)d_out;

    float* ws = (float*)d_ws;
    float*  s1     = ws;                                   // NN
    float*  s2     = s1 + NN;                              // NN
    float*  uv     = s2 + NN;                              // NN*128
    float*  agg    = uv + (size_t)NN * 128;                // NN*64
    float*  hbuf   = agg + (size_t)NN * 64;                // NN*64
    unsigned short* wh = (unsigned short*)(hbuf + (size_t)NN * 64);  // 24576 u16
    unsigned short* wl = wh + 24576;                                 // 24576 u16
    uint2*  sorted = (uint2*)(wl + 24576);                 // NE uint2
    int*    off    = (int*)(sorted + NE);                  // NN+1
    int*    bcount = off + NN + 1;                         // NBUK
    int*    bbase  = bcount + NBUK;                        // NBUK+1
    int*    bpos   = bbase + NBUK + 1;                     // NBUK
    uint2*  tmp    = (uint2*)uv;                           // alias: uv written later by k4a
    float*  G      = uv;                                   // alias (uv dead after k4b)
    float*  mbuf   = agg;                                  // alias (agg dead after k5h)

    const unsigned short* wmh = wh;          const unsigned short* wml = wl;
    const unsigned short* w1h = wh + 8192;   const unsigned short* w1l = wl + 8192;
    const unsigned short* w2h = wh + 16384;  const unsigned short* w2l = wl + 16384;

    hipMemsetAsync(bcount, 0, NBUK * sizeof(int), stream);

    k0prep    <<<96, 256, 0, stream>>>(Wp, Wn, w1, w2, cf, wh, wl);
    k1_scores <<<(NN+255)/256, 256, 0, stream>>>(x, attw, s1, s2);
    kh_coarse <<<NE/256, 256, 0, stream>>>(ei, bcount);
    ks_bscan  <<<1, 1024, 0, stream>>>(bcount, bbase, bpos);
    kscat1    <<<NE/256, 256, 0, stream>>>(ei, rf, bpos, tmp);
    kscat2    <<<NBUK, 256, 0, stream>>>(tmp, bbase, off, sorted);
    k4a_agg   <<<NN/4, 256, 0, stream>>>((const float2*)sorted, off, s1, s2, x, uv);
    k4b_mfma  <<<(NN+63)/64, 256, 0, stream>>>(uv, wmh, wml, agg);
    k5h_ln1   <<<(NN+255)/256, 256, 0, stream>>>(agg, x, g1, be1, hbuf);
    k5a_mfma  <<<(NN+63)/64, 256, 0, stream>>>(hbuf, w1h, w1l, b1, G);
    k5b_mfma  <<<(NN+63)/64, 256, 0, stream>>>(G, w2h, w2l, mbuf);
    k5c_ln2   <<<(NN+255)/256, 256, 0, stream>>>(mbuf, hbuf, b2, g2, be2, out);
}

// Round 9
// 460.870 us; speedup vs baseline: 2.4943x; 2.4943x over previous
//
#include <hip/hip_runtime.h>
#include <math.h>

#define NN 100000
#define NE 1600000
#define DD 64
#define NBUK 782          // ceil(NN/128), bucket = dst>>7
#define TILE 8192
#define NTB ((NE + TILE - 1) / TILE)   // 196 partition tiles

typedef __attribute__((ext_vector_type(8))) short short8;
typedef __attribute__((ext_vector_type(4))) float f32x4;

__device__ __forceinline__ float gelu_exact(float v) {
    return 0.5f * v * (1.0f + erff(v * 0.7071067811865475f));
}

__device__ __forceinline__ unsigned short f2bf(float f) {   // RNE
    unsigned u = __float_as_uint(f);
    return (unsigned short)((u + 0x7FFFu + ((u >> 16) & 1u)) >> 16);
}
__device__ __forceinline__ float bf2f(unsigned short h) {
    return __uint_as_float((unsigned)h << 16);
}
__device__ __forceinline__ void split8(const float* a, short8& hi, short8& lo) {
    float4 x0 = *(const float4*)a;
    float4 x1 = *(const float4*)(a + 4);
    float v[8] = {x0.x, x0.y, x0.z, x0.w, x1.x, x1.y, x1.z, x1.w};
    #pragma unroll
    for (int i = 0; i < 8; ++i) {
        unsigned short h = f2bf(v[i]);
        hi[i] = (short)h;
        lo[i] = (short)f2bf(v[i] - bf2f(h));
    }
}

__device__ __forceinline__ float wave_max64(float v) {
    #pragma unroll
    for (int o = 32; o > 0; o >>= 1) v = fmaxf(v, __shfl_xor(v, o));
    return v;
}
__device__ __forceinline__ float wave_sum64(float v) {
    #pragma unroll
    for (int o = 32; o > 0; o >>= 1) v += __shfl_xor(v, o);
    return v;
}

// K0P: build bf16 hi/lo split weight buffers
__global__ __launch_bounds__(256) void k0prep(
    const float* __restrict__ Wp, const float* __restrict__ Wn,
    const float* __restrict__ w1, const float* __restrict__ w2,
    const float* __restrict__ cf,
    unsigned short* __restrict__ wh, unsigned short* __restrict__ wl)
{
    int t = blockIdx.x * 256 + threadIdx.x;   // 24576 total
    float alpha = 1.0f / (1.0f + __expf(-cf[0]));
    float beta  = 1.0f - alpha;
    float v;
    if (t < 8192) {
        int d = t >> 7, k = t & 127;
        v = (k < 64) ? alpha * Wp[d * 64 + k] : beta * Wn[d * 64 + (k - 64)];
    } else if (t < 16384) {
        v = w1[t - 8192];
    } else {
        v = w2[t - 16384];
    }
    unsigned short h = f2bf(v);
    wh[t] = h;
    wl[t] = f2bf(v - bf2f(h));
}

// K1: per-node attention projections
__global__ __launch_bounds__(256) void k1_scores(
    const float* __restrict__ x, const float* __restrict__ attw,
    float* __restrict__ s1, float* __restrict__ s2)
{
    int n = blockIdx.x * 256 + threadIdx.x;
    if (n >= NN) return;
    const float4* x4 = (const float4*)(x + (size_t)n * DD);
    float a = 0.f, b = 0.f;
    #pragma unroll
    for (int i = 0; i < DD/4; ++i) {
        float4 v = x4[i];
        a += v.x*attw[4*i+0] + v.y*attw[4*i+1] + v.z*attw[4*i+2] + v.w*attw[4*i+3];
        b += v.x*attw[DD+4*i+0] + v.y*attw[DD+4*i+1] + v.z*attw[DD+4*i+2] + v.w*attw[DD+4*i+3];
    }
    s1[n] = a;
    s2[n] = b;
}

// KH: tiled coarse histogram — per-block LDS hist, then <=782 global atomics/block
__global__ __launch_bounds__(256) void kh_tiled(
    const int* __restrict__ ei, int* __restrict__ bcount)
{
    __shared__ int hist[NBUK];
    for (int i = threadIdx.x; i < NBUK; i += 256) hist[i] = 0;
    __syncthreads();
    int base = blockIdx.x * TILE;
    int end  = min(base + TILE, NE);
    for (int e = base + threadIdx.x; e < end; e += 256)
        atomicAdd(&hist[ei[NE + e] >> 7], 1);
    __syncthreads();
    for (int i = threadIdx.x; i < NBUK; i += 256) {
        int c = hist[i];
        if (c) atomicAdd(bcount + i, c);
    }
}

// KBS: single-block exclusive scan of 782 bucket counts -> bbase, bpos
__global__ __launch_bounds__(1024) void ks_bscan(
    const int* __restrict__ bcount, int* __restrict__ bbase, int* __restrict__ bpos)
{
    __shared__ int sa[1024], sb[1024];
    int t = threadIdx.x;
    int v = (t < NBUK) ? bcount[t] : 0;
    sa[t] = v;
    __syncthreads();
    int* s = sa; int* d = sb;
    #pragma unroll
    for (int o = 1; o < 1024; o <<= 1) {
        d[t] = s[t] + ((t >= o) ? s[t - o] : 0);
        __syncthreads();
        int* tmp = s; s = d; d = tmp;
    }
    if (t < NBUK) {
        int excl = s[t] - v;
        bbase[t] = excl;
        bpos[t]  = excl;
    }
    if (t == 0) bbase[NBUK] = NE;
}

// KSCAT1: tiled coarse partition. Per-block LDS hist -> one reservation atomic
// per (block,bucket) -> LDS-ticket scatter. Each block's writes to a bucket are
// one contiguous run assembled in its own CU/XCD L2.
__global__ __launch_bounds__(256) void kscat1(
    const int* __restrict__ ei, const float* __restrict__ rf,
    int* __restrict__ bpos, uint2* __restrict__ tmp)
{
    __shared__ int hist[NBUK];
    __shared__ int gbase[NBUK];
    for (int i = threadIdx.x; i < NBUK; i += 256) hist[i] = 0;
    __syncthreads();
    int base = blockIdx.x * TILE;
    int end  = min(base + TILE, NE);
    for (int e = base + threadIdx.x; e < end; e += 256)
        atomicAdd(&hist[ei[NE + e] >> 7], 1);
    __syncthreads();
    for (int i = threadIdx.x; i < NBUK; i += 256) {
        int c = hist[i];
        gbase[i] = c ? atomicAdd(bpos + i, c) : 0;
        hist[i] = 0;                      // reuse as ticket counter
    }
    __syncthreads();
    for (int e = base + threadIdx.x; e < end; e += 256) {
        int src = ei[e];
        int dst = ei[NE + e];
        int b = dst >> 7;
        int t = atomicAdd(&hist[b], 1);
        tmp[gbase[b] + t] =
            make_uint2((unsigned)src | ((unsigned)(dst & 127) << 17),
                       __float_as_uint(rf[e]));
    }
}

// KSCAT2: block-per-bucket fine sort: local histogram -> scan -> off[] + final scatter
__global__ __launch_bounds__(256) void kscat2(
    const uint2* __restrict__ tmp, const int* __restrict__ bbase,
    int* __restrict__ off, uint2* __restrict__ sorted)
{
    __shared__ int hist[128], scn[128], tick[128];
    int b   = blockIdx.x;
    int tid = threadIdx.x;
    int s = bbase[b], e = bbase[b + 1];

    if (tid < 128) { hist[tid] = 0; tick[tid] = 0; }
    __syncthreads();

    for (int i = s + tid; i < e; i += 256)
        atomicAdd(&hist[tmp[i].x >> 17], 1);
    __syncthreads();

    if (tid < 128) scn[tid] = hist[tid];
    __syncthreads();
    #pragma unroll
    for (int o = 1; o < 128; o <<= 1) {
        int v = (tid < 128 && tid >= o) ? scn[tid - o] : 0;
        __syncthreads();
        if (tid < 128) scn[tid] += v;
        __syncthreads();
    }

    int nb0 = b * 128;
    if (tid < 128 && nb0 + tid < NN) off[nb0 + tid] = s + scn[tid] - hist[tid];
    if (b == NBUK - 1 && tid == 0) off[NN] = NE;
    __syncthreads();

    for (int i = s + tid; i < e; i += 256) {
        uint2 pr = tmp[i];
        int l = pr.x >> 17;
        int t = atomicAdd(&tick[l], 1);
        int p = s + (scn[l] - hist[l]) + t;
        sorted[p] = make_uint2(pr.x & 0x1FFFFu, pr.y);
    }
}

// K4A: wave-per-node fused softmax + aggregation. uv[n] = {u, v}
__global__ __launch_bounds__(256) void k4a_agg(
    const float2* __restrict__ sorted, const int* __restrict__ off,
    const float* __restrict__ s1, const float* __restrict__ s2,
    const float* __restrict__ x, float* __restrict__ uv)
{
    int lane = threadIdx.x & 63;
    int n = blockIdx.x * 4 + (threadIdx.x >> 6);
    int r0 = off[n], r1 = off[n + 1];
    float s2n = s2[n];

    float m = -INFINITY, den = 0.f;
    for (int base = r0; base < r1; base += 64) {
        int idx = base + lane;
        float sc = -INFINITY;
        if (idx < r1) {
            float2 p = sorted[idx];
            sc = s1[__float_as_int(p.x)] + s2n;
        }
        float cm = wave_max64(sc);
        float nm = fmaxf(m, cm);
        float term = (idx < r1) ? __expf(sc - nm) : 0.f;
        den = den * __expf(m - nm) + wave_sum64(term);
        m = nm;
    }

    float u = 0.f, v = 0.f;
    for (int base = r0; base < r1; base += 64) {
        int idx = base + lane;
        int cnt = min(64, r1 - base);
        int srcl = 0; float rfl = 0.f, el = 0.f;
        if (idx < r1) {
            float2 p = sorted[idx];
            srcl = __float_as_int(p.x);
            rfl = p.y;
            el = __expf(s1[srcl] + s2n - m);
        }
        int j = 0;
        for (; j + 4 <= cnt; j += 4) {
            int   a0 = __shfl(srcl, j+0), a1 = __shfl(srcl, j+1);
            int   a2 = __shfl(srcl, j+2), a3 = __shfl(srcl, j+3);
            float e0 = __shfl(el, j+0), e1 = __shfl(el, j+1);
            float e2 = __shfl(el, j+2), e3 = __shfl(el, j+3);
            float f0 = __shfl(rfl, j+0), f1 = __shfl(rfl, j+1);
            float f2 = __shfl(rfl, j+2), f3 = __shfl(rfl, j+3);
            float x0 = x[(size_t)a0 * DD + lane];
            float x1 = x[(size_t)a1 * DD + lane];
            float x2 = x[(size_t)a2 * DD + lane];
            float x3 = x[(size_t)a3 * DD + lane];
            v += e0*x0 + e1*x1 + e2*x2 + e3*x3;
            u += e0*f0*x0 + e1*f1*x1 + e2*f2*x2 + e3*f3*x3;
        }
        for (; j < cnt; ++j) {
            int   sj = __shfl(srcl, j);
            float ej = __shfl(el,   j);
            float fj = __shfl(rfl,  j);
            float xv = x[(size_t)sj * DD + lane];
            v += ej * xv;
            u += ej * fj * xv;
        }
    }
    float inv = (r1 > r0) ? 1.f / den : 0.f;
    uv[(size_t)n * 2*DD + lane]      = u * inv;
    uv[(size_t)n * 2*DD + DD + lane] = v * inv;
}

// K4B: MFMA split-bf16 GEMM: agg[NN,64] = uv[NN,128] @ Bmix[128,64]
__global__ __launch_bounds__(256) void k4b_mfma(
    const float* __restrict__ uv, const unsigned short* __restrict__ wh,
    const unsigned short* __restrict__ wl, float* __restrict__ agg)
{
    int lane = threadIdx.x & 63;
    int wv   = threadIdx.x >> 6;
    int quad = lane >> 4, l16 = lane & 15;
    int nb = blockIdx.x * 64 + wv * 16;
    const float* arow = uv + (size_t)(nb + l16) * 128;

    f32x4 acc[4] = {};
    #pragma unroll
    for (int ks = 0; ks < 4; ++ks) {
        int k0 = ks * 32 + quad * 8;
        short8 ah, al;
        split8(arow + k0, ah, al);
        #pragma unroll
        for (int nt = 0; nt < 4; ++nt) {
            short8 bh = *(const short8*)(wh + (size_t)(nt*16 + l16)*128 + k0);
            short8 bl = *(const short8*)(wl + (size_t)(nt*16 + l16)*128 + k0);
            acc[nt] = __builtin_amdgcn_mfma_f32_16x16x32_bf16(ah, bh, acc[nt], 0, 0, 0);
            acc[nt] = __builtin_amdgcn_mfma_f32_16x16x32_bf16(al, bh, acc[nt], 0, 0, 0);
            acc[nt] = __builtin_amdgcn_mfma_f32_16x16x32_bf16(ah, bl, acc[nt], 0, 0, 0);
        }
    }
    #pragma unroll
    for (int r = 0; r < 4; ++r) {
        int n = nb + quad * 4 + r;
        if (n < NN) {
            #pragma unroll
            for (int nt = 0; nt < 4; ++nt)
                agg[(size_t)n * 64 + nt*16 + l16] = acc[nt][r];
        }
    }
}

// K5H: h = LN1(gelu(agg) + x) -> hbuf
__global__ __launch_bounds__(256) void k5h_ln1(
    const float* __restrict__ agg, const float* __restrict__ x,
    const float* __restrict__ g1, const float* __restrict__ be1,
    float* __restrict__ hbuf)
{
    int n = blockIdx.x * 256 + threadIdx.x;
    if (n >= NN) return;
    float h[DD];
    const float4* a4 = (const float4*)(agg + (size_t)n * DD);
    const float4* x4 = (const float4*)(x   + (size_t)n * DD);
    #pragma unroll
    for (int i = 0; i < DD/4; ++i) {
        float4 av = a4[i];
        float4 xv = x4[i];
        h[4*i+0] = gelu_exact(av.x) + xv.x;
        h[4*i+1] = gelu_exact(av.y) + xv.y;
        h[4*i+2] = gelu_exact(av.z) + xv.z;
        h[4*i+3] = gelu_exact(av.w) + xv.w;
    }
    float mu = 0.f;
    #pragma unroll
    for (int d = 0; d < DD; ++d) mu += h[d];
    mu *= (1.0f/DD);
    float var = 0.f;
    #pragma unroll
    for (int d = 0; d < DD; ++d) { float t = h[d]-mu; var += t*t; }
    var *= (1.0f/DD);
    float rs = rsqrtf(var + 1e-5f);
    float4* h4 = (float4*)(hbuf + (size_t)n * DD);
    #pragma unroll
    for (int i = 0; i < DD/4; ++i) {
        float4 o;
        o.x = (h[4*i+0]-mu)*rs*g1[4*i+0] + be1[4*i+0];
        o.y = (h[4*i+1]-mu)*rs*g1[4*i+1] + be1[4*i+1];
        o.z = (h[4*i+2]-mu)*rs*g1[4*i+2] + be1[4*i+2];
        o.w = (h[4*i+3]-mu)*rs*g1[4*i+3] + be1[4*i+3];
        h4[i] = o;
    }
}

// K5A: MFMA GEMM1 + gelu: G[NN,128] = gelu(h[NN,64] @ w1^T + b1)
__global__ __launch_bounds__(256) void k5a_mfma(
    const float* __restrict__ hbuf, const unsigned short* __restrict__ w1h,
    const unsigned short* __restrict__ w1l, const float* __restrict__ bb1,
    float* __restrict__ G)
{
    int lane = threadIdx.x & 63;
    int wv   = threadIdx.x >> 6;
    int quad = lane >> 4, l16 = lane & 15;
    int nb = blockIdx.x * 64 + wv * 16;
    const float* arow = hbuf + (size_t)(nb + l16) * 64;

    f32x4 acc[8] = {};
    #pragma unroll
    for (int ks = 0; ks < 2; ++ks) {
        int k0 = ks * 32 + quad * 8;
        short8 ah, al;
        split8(arow + k0, ah, al);
        #pragma unroll
        for (int nt = 0; nt < 8; ++nt) {
            short8 bh = *(const short8*)(w1h + (size_t)(nt*16 + l16)*64 + k0);
            short8 bl = *(const short8*)(w1l + (size_t)(nt*16 + l16)*64 + k0);
            acc[nt] = __builtin_amdgcn_mfma_f32_16x16x32_bf16(ah, bh, acc[nt], 0, 0, 0);
            acc[nt] = __builtin_amdgcn_mfma_f32_16x16x32_bf16(al, bh, acc[nt], 0, 0, 0);
            acc[nt] = __builtin_amdgcn_mfma_f32_16x16x32_bf16(ah, bl, acc[nt], 0, 0, 0);
        }
    }
    #pragma unroll
    for (int nt = 0; nt < 8; ++nt) {
        float b1v = bb1[nt*16 + l16];
        #pragma unroll
        for (int r = 0; r < 4; ++r) {
            int n = nb + quad * 4 + r;
            if (n < NN)
                G[(size_t)n * 128 + nt*16 + l16] = gelu_exact(acc[nt][r] + b1v);
        }
    }
}

// K5B: MFMA GEMM2: mbuf[NN,64] = G[NN,128] @ w2^T
__global__ __launch_bounds__(256) void k5b_mfma(
    const float* __restrict__ G, const unsigned short* __restrict__ w2h,
    const unsigned short* __restrict__ w2l, float* __restrict__ mbuf)
{
    int lane = threadIdx.x & 63;
    int wv   = threadIdx.x >> 6;
    int quad = lane >> 4, l16 = lane & 15;
    int nb = blockIdx.x * 64 + wv * 16;
    const float* arow = G + (size_t)(nb + l16) * 128;

    f32x4 acc[4] = {};
    #pragma unroll
    for (int ks = 0; ks < 4; ++ks) {
        int k0 = ks * 32 + quad * 8;
        short8 ah, al;
        split8(arow + k0, ah, al);
        #pragma unroll
        for (int nt = 0; nt < 4; ++nt) {
            short8 bh = *(const short8*)(w2h + (size_t)(nt*16 + l16)*128 + k0);
            short8 bl = *(const short8*)(w2l + (size_t)(nt*16 + l16)*128 + k0);
            acc[nt] = __builtin_amdgcn_mfma_f32_16x16x32_bf16(ah, bh, acc[nt], 0, 0, 0);
            acc[nt] = __builtin_amdgcn_mfma_f32_16x16x32_bf16(al, bh, acc[nt], 0, 0, 0);
            acc[nt] = __builtin_amdgcn_mfma_f32_16x16x32_bf16(ah, bl, acc[nt], 0, 0, 0);
        }
    }
    #pragma unroll
    for (int r = 0; r < 4; ++r) {
        int n = nb + quad * 4 + r;
        if (n < NN) {
            #pragma unroll
            for (int nt = 0; nt < 4; ++nt)
                mbuf[(size_t)n * 64 + nt*16 + l16] = acc[nt][r];
        }
    }
}

// K5C: out = LN2(mbuf + hbuf + b2)
__global__ __launch_bounds__(256) void k5c_ln2(
    const float* __restrict__ mbuf, const float* __restrict__ hbuf,
    const float* __restrict__ bb2,
    const float* __restrict__ g2, const float* __restrict__ be2,
    float* __restrict__ out)
{
    int n = blockIdx.x * 256 + threadIdx.x;
    if (n >= NN) return;
    float m[DD];
    const float4* m4 = (const float4*)(mbuf + (size_t)n * DD);
    const float4* h4 = (const float4*)(hbuf + (size_t)n * DD);
    #pragma unroll
    for (int i = 0; i < DD/4; ++i) {
        float4 mv = m4[i];
        float4 hv = h4[i];
        m[4*i+0] = mv.x + hv.x + bb2[4*i+0];
        m[4*i+1] = mv.y + hv.y + bb2[4*i+1];
        m[4*i+2] = mv.z + hv.z + bb2[4*i+2];
        m[4*i+3] = mv.w + hv.w + bb2[4*i+3];
    }
    float mu = 0.f;
    #pragma unroll
    for (int d = 0; d < DD; ++d) mu += m[d];
    mu *= (1.0f/DD);
    float var = 0.f;
    #pragma unroll
    for (int d = 0; d < DD; ++d) { float t = m[d]-mu; var += t*t; }
    var *= (1.0f/DD);
    float rs = rsqrtf(var + 1e-5f);
    float4* o4 = (float4*)(out + (size_t)n * DD);
    #pragma unroll
    for (int i = 0; i < DD/4; ++i) {
        float4 o;
        o.x = (m[4*i+0]-mu)*rs*g2[4*i+0] + be2[4*i+0];
        o.y = (m[4*i+1]-mu)*rs*g2[4*i+1] + be2[4*i+1];
        o.z = (m[4*i+2]-mu)*rs*g2[4*i+2] + be2[4*i+2];
        o.w = (m[4*i+3]-mu)*rs*g2[4*i+3] + be2[4*i+3];
        o4[i] = o;
    }
}

extern "C" void kernel_launch(void* const* d_in, const int* in_sizes, int n_in,
                              void* d_out, int out_size, void* d_ws, size_t ws_size,
                              hipStream_t stream) {
    const float* x    = (const float*)d_in[0];
    const int*   ei   = (const int*)d_in[1];
    const float* rf   = (const float*)d_in[2];
    const float* Wp   = (const float*)d_in[3];
    const float* Wn   = (const float*)d_in[4];
    const float* attw = (const float*)d_in[5];
    const float* cf   = (const float*)d_in[6];
    const float* w1   = (const float*)d_in[7];
    const float* b1   = (const float*)d_in[8];
    const float* w2   = (const float*)d_in[9];
    const float* b2   = (const float*)d_in[10];
    const float* g1   = (const float*)d_in[11];
    const float* be1  = (const float*)d_in[12];
    const float* g2   = (const float*)d_in[13];
    const float* be2  = (const float*)d_in[14];
    float* out = (float*)d_out;

    float* ws = (float*)d_ws;
    float*  s1     = ws;                                   // NN
    float*  s2     = s1 + NN;                              // NN
    float*  uv     = s2 + NN;                              // NN*128
    float*  agg    = uv + (size_t)NN * 128;                // NN*64
    float*  hbuf   = agg + (size_t)NN * 64;                // NN*64
    unsigned short* wh = (unsigned short*)(hbuf + (size_t)NN * 64);  // 24576 u16
    unsigned short* wl = wh + 24576;                                 // 24576 u16
    uint2*  sorted = (uint2*)(wl + 24576);                 // NE uint2
    int*    off    = (int*)(sorted + NE);                  // NN+1
    int*    bcount = off + NN + 1;                         // NBUK
    int*    bbase  = bcount + NBUK;                        // NBUK+1
    int*    bpos   = bbase + NBUK + 1;                     // NBUK
    uint2*  tmp    = (uint2*)uv;                           // alias: uv written later by k4a
    float*  G      = uv;                                   // alias (uv dead after k4b)
    float*  mbuf   = agg;                                  // alias (agg dead after k5h)

    const unsigned short* wmh = wh;          const unsigned short* wml = wl;
    const unsigned short* w1h = wh + 8192;   const unsigned short* w1l = wl + 8192;
    const unsigned short* w2h = wh + 16384;  const unsigned short* w2l = wl + 16384;

    hipMemsetAsync(bcount, 0, NBUK * sizeof(int), stream);

    k0prep    <<<96, 256, 0, stream>>>(Wp, Wn, w1, w2, cf, wh, wl);
    k1_scores <<<(NN+255)/256, 256, 0, stream>>>(x, attw, s1, s2);
    kh_tiled  <<<NTB, 256, 0, stream>>>(ei, bcount);
    ks_bscan  <<<1, 1024, 0, stream>>>(bcount, bbase, bpos);
    kscat1    <<<NTB, 256, 0, stream>>>(ei, rf, bpos, tmp);
    kscat2    <<<NBUK, 256, 0, stream>>>(tmp, bbase, off, sorted);
    k4a_agg   <<<NN/4, 256, 0, stream>>>((const float2*)sorted, off, s1, s2, x, uv);
    k4b_mfma  <<<(NN+63)/64, 256, 0, stream>>>(uv, wmh, wml, agg);
    k5h_ln1   <<<(NN+255)/256, 256, 0, stream>>>(agg, x, g1, be1, hbuf);
    k5a_mfma  <<<(NN+63)/64, 256, 0, stream>>>(hbuf, w1h, w1l, b1, G);
    k5b_mfma  <<<(NN+63)/64, 256, 0, stream>>>(G, w2h, w2l, mbuf);
    k5c_ln2   <<<(NN+255)/256, 256, 0, stream>>>(mbuf, hbuf, b2, g2, be2, out);
}